// Round 2
// baseline (216.893 us; speedup 1.0000x reference)
//
#include <hip/hip_runtime.h>

// Problem: B=8192, T=128, D=7, I=128, C=10, H=64, L=128
// ws layout (floats) — identical footprint to round 1 (39.6 MB):
//   sT      [896][8192]      off 0
//   LPpad   [16384][12]      off 7,340,032
//   attnT   [128][8192]      off 7,536,640
//   partial [16][8192][10]   off 8,585,216

#define BB 8192
#define TT 128
#define II 128
#define CC 10
#define HH 64

#define OFF_S   0
#define OFF_LP  7340032
#define OFF_AT  7536640
#define OFF_PT  8585216

// ---------------- Kernel 1: z GEMM + softsign, sT[td][b] --------------------
// tile M=64 (td) x N=256 (b), K chunked 4x32. 8x8 micro-tile.
__global__ __launch_bounds__(256) void zs_kernel(
    const float* __restrict__ mask, const float* __restrict__ x,
    const float* __restrict__ thr, float* __restrict__ sT) {
  __shared__ float As[32 * 68];    // [k][m], stride 68 (16B-aligned rows)
  __shared__ float Bs[32 * 260];   // [k][n], stride 260
  const int ng = blockIdx.x;       // 0..31 over b (256 each)
  const int mt = blockIdx.y;       // 0..13 over td (64 each)
  const int tid = threadIdx.x;
  const int tm = tid & 7;          // 8 m-threads x 8 rows
  const int tn = tid >> 3;         // 32 n-threads x 8 cols

  float acc[8][8];
#pragma unroll
  for (int i = 0; i < 8; ++i)
#pragma unroll
    for (int j = 0; j < 8; ++j) acc[i][j] = 0.f;

  for (int kc = 0; kc < 4; ++kc) {
    __syncthreads();
    // stage A: 64 rows x 32 k = 512 float4, 2/thread (transpose to [k][m])
#pragma unroll
    for (int j = 0; j < 2; ++j) {
      int f = tid + 256 * j;
      int r = f >> 3, k4 = f & 7;
      float4 a = *(const float4*)(mask + (size_t)(mt * 64 + r) * II + kc * 32 + k4 * 4);
      As[(k4 * 4 + 0) * 68 + r] = a.x; As[(k4 * 4 + 1) * 68 + r] = a.y;
      As[(k4 * 4 + 2) * 68 + r] = a.z; As[(k4 * 4 + 3) * 68 + r] = a.w;
    }
    // stage B: 256 rows x 32 k = 2048 float4, 8/thread
#pragma unroll
    for (int j = 0; j < 8; ++j) {
      int f = tid + 256 * j;
      int r = f >> 3, k4 = f & 7;
      float4 b = *(const float4*)(x + (size_t)(ng * 256 + r) * II + kc * 32 + k4 * 4);
      Bs[(k4 * 4 + 0) * 260 + r] = b.x; Bs[(k4 * 4 + 1) * 260 + r] = b.y;
      Bs[(k4 * 4 + 2) * 260 + r] = b.z; Bs[(k4 * 4 + 3) * 260 + r] = b.w;
    }
    __syncthreads();

#pragma unroll 4
    for (int k = 0; k < 32; ++k) {
      float4 a0 = *(const float4*)&As[k * 68 + tm * 8];
      float4 a1 = *(const float4*)&As[k * 68 + tm * 8 + 4];
      float4 b0 = *(const float4*)&Bs[k * 260 + tn * 8];
      float4 b1 = *(const float4*)&Bs[k * 260 + tn * 8 + 4];
      float am[8] = {a0.x, a0.y, a0.z, a0.w, a1.x, a1.y, a1.z, a1.w};
      float bn[8] = {b0.x, b0.y, b0.z, b0.w, b1.x, b1.y, b1.z, b1.w};
#pragma unroll
      for (int i = 0; i < 8; ++i)
#pragma unroll
        for (int j = 0; j < 8; ++j) acc[i][j] = fmaf(am[i], bn[j], acc[i][j]);
    }
  }

#pragma unroll
  for (int i = 0; i < 8; ++i) {
    int m = mt * 64 + tm * 8 + i;
    float th = thr[m];
    float o[8];
#pragma unroll
    for (int j = 0; j < 8; ++j) {
      float z = acc[i][j] - th;
      o[j] = 0.5f * (z / (1.f + fabsf(z)) + 1.f);
    }
    float* dst = sT + (size_t)m * BB + ng * 256 + tn * 8;
    *(float4*)(dst) = make_float4(o[0], o[1], o[2], o[3]);
    *(float4*)(dst + 4) = make_float4(o[4], o[5], o[6], o[7]);
  }
}

// ---------------- Kernel 2: leaf softmax, padded to 12 ----------------------
__global__ __launch_bounds__(256) void leafsm_kernel(
    const float* __restrict__ lo, float* __restrict__ lp) {
  int idx = blockIdx.x * 256 + threadIdx.x;  // 0..16383 = (t,l)
  const float* row = lo + (size_t)idx * CC;
  float v[CC];
  float m = -1e30f;
#pragma unroll
  for (int c = 0; c < CC; ++c) { v[c] = row[c]; m = fmaxf(m, v[c]); }
  float s = 0.f;
#pragma unroll
  for (int c = 0; c < CC; ++c) { v[c] = __expf(v[c] - m); s += v[c]; }
  float inv = 1.f / s;
  float* o = lp + (size_t)idx * 12;
#pragma unroll
  for (int c = 0; c < CC; ++c) o[c] = v[c] * inv;
  o[10] = 0.f; o[11] = 0.f;
}

// ---------------- Kernel 3: fused attention MLP + softmax -> attnT[t][b] ----
// block = 16 batches; W1/W2 share one 32KB LDS buffer; vectorized inner loops.
__global__ __launch_bounds__(256) void attn_kernel(
    const float* __restrict__ x, const float* __restrict__ W1,
    const float* __restrict__ b1, const float* __restrict__ W2,
    const float* __restrict__ b2, float* __restrict__ attnT) {
  __shared__ float xsT[128 * 18];   // [k][b] stride 18
  __shared__ float Ws[8192];        // W1 then W2 (reused)
  __shared__ float hids[64 * 18];   // [h][b] stride 18
  __shared__ float lgt[16 * 128];   // [b][t]
  __shared__ float mred[16], sred[16];
  const int tid = threadIdx.x;
  const int bbase = blockIdx.x * 16;

  // stage x transposed: 16 rows x 128 = 512 float4, 2/thread
#pragma unroll
  for (int j = 0; j < 2; ++j) {
    int f = tid + 256 * j;
    int r = f >> 5, k4 = f & 31;
    float4 v = *(const float4*)(x + (size_t)(bbase + r) * II + k4 * 4);
    xsT[(k4 * 4 + 0) * 18 + r] = v.x; xsT[(k4 * 4 + 1) * 18 + r] = v.y;
    xsT[(k4 * 4 + 2) * 18 + r] = v.z; xsT[(k4 * 4 + 3) * 18 + r] = v.w;
  }
  // stage W1 (8192 floats)
#pragma unroll
  for (int j = 0; j < 8; ++j)
    ((float4*)Ws)[tid + 256 * j] = ((const float4*)W1)[tid + 256 * j];
  __syncthreads();

  // hidden: 16b x 64h outputs; thread = (bt 0..7, ht 0..31), micro 2b x 2h
  const int bt = tid >> 5, ht = tid & 31;
  float bh0 = b1[ht * 2], bh1 = b1[ht * 2 + 1];
  float a00 = bh0, a01 = bh1, a10 = bh0, a11 = bh1;
#pragma unroll 8
  for (int k = 0; k < 128; ++k) {
    float2 xv = *(const float2*)&xsT[k * 18 + bt * 2];
    float2 wv = *(const float2*)&Ws[k * 64 + ht * 2];
    a00 = fmaf(xv.x, wv.x, a00); a01 = fmaf(xv.x, wv.y, a01);
    a10 = fmaf(xv.y, wv.x, a10); a11 = fmaf(xv.y, wv.y, a11);
  }
  a00 = fmaxf(a00, 0.f); a01 = fmaxf(a01, 0.f);
  a10 = fmaxf(a10, 0.f); a11 = fmaxf(a11, 0.f);
  hids[(ht * 2 + 0) * 18 + bt * 2 + 0] = a00;
  hids[(ht * 2 + 1) * 18 + bt * 2 + 0] = a01;
  hids[(ht * 2 + 0) * 18 + bt * 2 + 1] = a10;
  hids[(ht * 2 + 1) * 18 + bt * 2 + 1] = a11;
  __syncthreads();

  // stage W2 into the same buffer
#pragma unroll
  for (int j = 0; j < 8; ++j)
    ((float4*)Ws)[tid + 256 * j] = ((const float4*)W2)[tid + 256 * j];
  __syncthreads();

  // logits: 16b x 128t; thread = (bt2 0..7, tt 0..31), micro 2b x 4t
  const int bt2 = tid >> 5, tt = tid & 31;
  float l0[4], l1[4];
#pragma unroll
  for (int j = 0; j < 4; ++j) { l0[j] = b2[tt * 4 + j]; l1[j] = l0[j]; }
#pragma unroll 4
  for (int k = 0; k < 64; ++k) {
    float2 hv = *(const float2*)&hids[k * 18 + bt2 * 2];
    float4 wv = *(const float4*)&Ws[k * 128 + tt * 4];
    float w[4] = {wv.x, wv.y, wv.z, wv.w};
#pragma unroll
    for (int j = 0; j < 4; ++j) {
      l0[j] = fmaf(hv.x, w[j], l0[j]);
      l1[j] = fmaf(hv.y, w[j], l1[j]);
    }
  }
#pragma unroll
  for (int j = 0; j < 4; ++j) {
    lgt[(bt2 * 2 + 0) * 128 + tt * 4 + j] = l0[j];
    lgt[(bt2 * 2 + 1) * 128 + tt * 4 + j] = l1[j];
  }
  __syncthreads();

  if (tid < 16) {
    float m = -1e30f;
    for (int t = 0; t < TT; ++t) m = fmaxf(m, lgt[tid * 128 + t]);
    float s = 0.f;
    for (int t = 0; t < TT; ++t) s += __expf(lgt[tid * 128 + t] - m);
    mred[tid] = m; sred[tid] = 1.f / s;
  }
  __syncthreads();

#pragma unroll
  for (int j = 0; j < 8; ++j) {
    int idx = tid + 256 * j;
    int r = idx & 15, t = idx >> 4;
    float a = __expf(lgt[r * 128 + t] - mred[r]) * sred[r];
    attnT[(size_t)t * BB + bbase + r] = a;
  }
}

// ---------------- Kernel 4: main contraction --------------------------------
// grid (32 b-groups of 256, 16 t-chunks of 8); block 256 = 4 waves.
// wave w: trees {w*2, w*2+1}; lane covers 4 batches (b0 + {0,64,128,192}).
// LP rows read via wave-uniform global float4 broadcast loads (no LDS pipe).
__global__ __launch_bounds__(256) void main_kernel(
    const float* __restrict__ sT, const float* __restrict__ attnT,
    const float* __restrict__ lp, float* __restrict__ partial) {
  __shared__ float red[4 * 256 * 11];  // [w][b_local][c] pad 11 = 45KB
  const int bg = blockIdx.x, tc = blockIdx.y;
  const int tid = threadIdx.x;
  const int w = tid >> 6, lane = tid & 63;
  const int b0 = bg * 256 + lane;

  float acc[4][10];
#pragma unroll
  for (int q = 0; q < 4; ++q)
#pragma unroll
    for (int c = 0; c < 10; ++c) acc[q][c] = 0.f;

#pragma unroll 1
  for (int it = 0; it < 2; ++it) {
    const int t = tc * 8 + w * 2 + it;
    float s[4][7], A[4];
#pragma unroll
    for (int q = 0; q < 4; ++q) {
#pragma unroll
      for (int d = 0; d < 7; ++d)
        s[q][d] = sT[(size_t)(t * 7 + d) * BB + b0 + q * 64];
      A[q] = attnT[(size_t)t * BB + b0 + q * 64];
    }

    // phi: pl over depths 0..2 (8), ph over depths 3..6 with attn folded (16)
    float pl[4][8], ph[4][16];
#pragma unroll
    for (int q = 0; q < 4; ++q) {
      float s0 = s[q][0], s1 = s[q][1], s2 = s[q][2];
      float t2[4];
      t2[0] = s0 * s1; t2[1] = (1.f - s0) * s1;
      t2[2] = s0 * (1.f - s1); t2[3] = (1.f - s0) * (1.f - s1);
#pragma unroll
      for (int j = 0; j < 4; ++j) {
        pl[q][j] = t2[j] * s2; pl[q][j + 4] = t2[j] * (1.f - s2);
      }
      float g1a = A[q] * s[q][3], g1b = A[q] * (1.f - s[q][3]);
      float g2[4];
      g2[0] = g1a * s[q][4]; g2[1] = g1b * s[q][4];
      g2[2] = g1a * (1.f - s[q][4]); g2[3] = g1b * (1.f - s[q][4]);
      float g3[8];
#pragma unroll
      for (int j = 0; j < 4; ++j) { g3[j] = g2[j] * s[q][5]; g3[j + 4] = g2[j] * (1.f - s[q][5]); }
#pragma unroll
      for (int h = 0; h < 8; ++h) { ph[q][h] = g3[h] * s[q][6]; ph[q][h + 8] = g3[h] * (1.f - s[q][6]); }
    }

    const float4* lpt = (const float4*)(lp + (size_t)t * 128 * 12);
    // lo rolled (register-rotate pl), hi unrolled -> constant indices, small body
#pragma unroll 1
    for (int lo = 0; lo < 8; ++lo) {
      float plc[4];
#pragma unroll
      for (int q = 0; q < 4; ++q) plc[q] = pl[q][0];
#pragma unroll
      for (int hi = 0; hi < 16; ++hi) {
        const float4* row = lpt + (size_t)(hi * 8 + lo) * 3;
        float4 va = row[0], vb = row[1], vc = row[2];
#pragma unroll
        for (int q = 0; q < 4; ++q) {
          float p = plc[q] * ph[q][hi];
          acc[q][0] = fmaf(p, va.x, acc[q][0]);
          acc[q][1] = fmaf(p, va.y, acc[q][1]);
          acc[q][2] = fmaf(p, va.z, acc[q][2]);
          acc[q][3] = fmaf(p, va.w, acc[q][3]);
          acc[q][4] = fmaf(p, vb.x, acc[q][4]);
          acc[q][5] = fmaf(p, vb.y, acc[q][5]);
          acc[q][6] = fmaf(p, vb.z, acc[q][6]);
          acc[q][7] = fmaf(p, vb.w, acc[q][7]);
          acc[q][8] = fmaf(p, vc.x, acc[q][8]);
          acc[q][9] = fmaf(p, vc.y, acc[q][9]);
        }
      }
      // rotate pl left by one
#pragma unroll
      for (int q = 0; q < 4; ++q) {
#pragma unroll
        for (int j = 0; j < 7; ++j) pl[q][j] = pl[q][j + 1];
      }
    }
  }

#pragma unroll
  for (int q = 0; q < 4; ++q)
#pragma unroll
    for (int c = 0; c < 10; ++c)
      red[(w * 256 + lane + q * 64) * 11 + c] = acc[q][c];
  __syncthreads();

#pragma unroll
  for (int c = 0; c < 10; ++c) {
    float v = red[(0 * 256 + tid) * 11 + c] + red[(1 * 256 + tid) * 11 + c] +
              red[(2 * 256 + tid) * 11 + c] + red[(3 * 256 + tid) * 11 + c];
    partial[((size_t)tc * BB + bg * 256 + tid) * 10 + c] = v;
  }
}

// ---------------- Kernel 5: final reduce over 16 t-chunks -------------------
__global__ __launch_bounds__(256) void reduce_kernel(
    const float* __restrict__ partial, float* __restrict__ out) {
  int idx = blockIdx.x * 256 + threadIdx.x;  // 0..81919
  float s = 0.f;
#pragma unroll
  for (int tc = 0; tc < 16; ++tc) s += partial[(size_t)tc * (BB * CC) + idx];
  out[idx] = s;
}

// ---------------------------------------------------------------------------
extern "C" void kernel_launch(void* const* d_in, const int* in_sizes, int n_in,
                              void* d_out, int out_size, void* d_ws, size_t ws_size,
                              hipStream_t stream) {
  const float* x    = (const float*)d_in[0];
  const float* mask = (const float*)d_in[1];
  const float* thr  = (const float*)d_in[2];
  const float* lo   = (const float*)d_in[3];
  const float* W1   = (const float*)d_in[4];
  const float* b1   = (const float*)d_in[5];
  const float* W2   = (const float*)d_in[6];
  const float* b2   = (const float*)d_in[7];
  float* out = (float*)d_out;
  float* ws  = (float*)d_ws;

  float* sT      = ws + OFF_S;
  float* LPpad   = ws + OFF_LP;
  float* attnT   = ws + OFF_AT;
  float* partial = ws + OFF_PT;

  zs_kernel<<<dim3(32, 14), 256, 0, stream>>>(mask, x, thr, sT);
  leafsm_kernel<<<64, 256, 0, stream>>>(lo, LPpad);
  attn_kernel<<<512, 256, 0, stream>>>(x, W1, b1, W2, b2, attnT);
  main_kernel<<<dim3(32, 16), 256, 0, stream>>>(sT, attnT, LPpad, partial);
  reduce_kernel<<<320, 256, 0, stream>>>(partial, out);
}

// Round 3
// 162.369 us; speedup vs baseline: 1.3358x; 1.3358x over previous
//
#include <hip/hip_runtime.h>
#include <hip/hip_fp16.h>

// Problem: B=8192, T=128, D=7, I=128, C=10, H=64, L=128
// ws layout (floats) — 39.6 MB (same footprint as round 1):
//   sT      [896][8192]        off 0
//   LPpad   [16384][12]        off 7,340,032
//   attnT   [128][8192]        off 7,536,640
//   partial fp16 [32][8192][10] off 8,585,216 (2.62M half = 1.31M float slots)

#define BB 8192
#define TT 128
#define II 128
#define CC 10
#define HH 64

#define OFF_S   0
#define OFF_LP  7340032
#define OFF_AT  7536640
#define OFF_PT  8585216

// ---------------- Kernel 1: z GEMM + softsign, sT[td][b] --------------------
__global__ __launch_bounds__(256) void zs_kernel(
    const float* __restrict__ mask, const float* __restrict__ x,
    const float* __restrict__ thr, float* __restrict__ sT) {
  __shared__ float As[32 * 68];    // [k][m]
  __shared__ float Bs[32 * 260];   // [k][n]
  const int ng = blockIdx.x;       // 0..31 over b (256 each)
  const int mt = blockIdx.y;       // 0..13 over td (64 each)
  const int tid = threadIdx.x;
  const int tm = tid & 7;
  const int tn = tid >> 3;

  float acc[8][8];
#pragma unroll
  for (int i = 0; i < 8; ++i)
#pragma unroll
    for (int j = 0; j < 8; ++j) acc[i][j] = 0.f;

  for (int kc = 0; kc < 4; ++kc) {
    __syncthreads();
#pragma unroll
    for (int j = 0; j < 2; ++j) {
      int f = tid + 256 * j;
      int r = f >> 3, k4 = f & 7;
      float4 a = *(const float4*)(mask + (size_t)(mt * 64 + r) * II + kc * 32 + k4 * 4);
      As[(k4 * 4 + 0) * 68 + r] = a.x; As[(k4 * 4 + 1) * 68 + r] = a.y;
      As[(k4 * 4 + 2) * 68 + r] = a.z; As[(k4 * 4 + 3) * 68 + r] = a.w;
    }
#pragma unroll
    for (int j = 0; j < 8; ++j) {
      int f = tid + 256 * j;
      int r = f >> 3, k4 = f & 7;
      float4 b = *(const float4*)(x + (size_t)(ng * 256 + r) * II + kc * 32 + k4 * 4);
      Bs[(k4 * 4 + 0) * 260 + r] = b.x; Bs[(k4 * 4 + 1) * 260 + r] = b.y;
      Bs[(k4 * 4 + 2) * 260 + r] = b.z; Bs[(k4 * 4 + 3) * 260 + r] = b.w;
    }
    __syncthreads();

#pragma unroll 4
    for (int k = 0; k < 32; ++k) {
      float4 a0 = *(const float4*)&As[k * 68 + tm * 8];
      float4 a1 = *(const float4*)&As[k * 68 + tm * 8 + 4];
      float4 b0 = *(const float4*)&Bs[k * 260 + tn * 8];
      float4 b1 = *(const float4*)&Bs[k * 260 + tn * 8 + 4];
      float am[8] = {a0.x, a0.y, a0.z, a0.w, a1.x, a1.y, a1.z, a1.w};
      float bn[8] = {b0.x, b0.y, b0.z, b0.w, b1.x, b1.y, b1.z, b1.w};
#pragma unroll
      for (int i = 0; i < 8; ++i)
#pragma unroll
        for (int j = 0; j < 8; ++j) acc[i][j] = fmaf(am[i], bn[j], acc[i][j]);
    }
  }

#pragma unroll
  for (int i = 0; i < 8; ++i) {
    int m = mt * 64 + tm * 8 + i;
    float th = thr[m];
    float o[8];
#pragma unroll
    for (int j = 0; j < 8; ++j) {
      float z = acc[i][j] - th;
      o[j] = 0.5f * (z / (1.f + fabsf(z)) + 1.f);
    }
    float* dst = sT + (size_t)m * BB + ng * 256 + tn * 8;
    *(float4*)(dst) = make_float4(o[0], o[1], o[2], o[3]);
    *(float4*)(dst + 4) = make_float4(o[4], o[5], o[6], o[7]);
  }
}

// ---------------- Kernel 2: leaf softmax, padded to 12 ----------------------
__global__ __launch_bounds__(256) void leafsm_kernel(
    const float* __restrict__ lo, float* __restrict__ lp) {
  int idx = blockIdx.x * 256 + threadIdx.x;
  const float* row = lo + (size_t)idx * CC;
  float v[CC];
  float m = -1e30f;
#pragma unroll
  for (int c = 0; c < CC; ++c) { v[c] = row[c]; m = fmaxf(m, v[c]); }
  float s = 0.f;
#pragma unroll
  for (int c = 0; c < CC; ++c) { v[c] = __expf(v[c] - m); s += v[c]; }
  float inv = 1.f / s;
  float* o = lp + (size_t)idx * 12;
#pragma unroll
  for (int c = 0; c < CC; ++c) o[c] = v[c] * inv;
  o[10] = 0.f; o[11] = 0.f;
}

// ---------------- Kernel 3: fused attention MLP + softmax -> attnT[t][b] ----
__global__ __launch_bounds__(256) void attn_kernel(
    const float* __restrict__ x, const float* __restrict__ W1,
    const float* __restrict__ b1, const float* __restrict__ W2,
    const float* __restrict__ b2, float* __restrict__ attnT) {
  __shared__ float xsT[128 * 18];
  __shared__ float Ws[8192];
  __shared__ float hids[64 * 18];
  __shared__ float lgt[16 * 128];
  __shared__ float mred[16], sred[16];
  const int tid = threadIdx.x;
  const int bbase = blockIdx.x * 16;

#pragma unroll
  for (int j = 0; j < 2; ++j) {
    int f = tid + 256 * j;
    int r = f >> 5, k4 = f & 31;
    float4 v = *(const float4*)(x + (size_t)(bbase + r) * II + k4 * 4);
    xsT[(k4 * 4 + 0) * 18 + r] = v.x; xsT[(k4 * 4 + 1) * 18 + r] = v.y;
    xsT[(k4 * 4 + 2) * 18 + r] = v.z; xsT[(k4 * 4 + 3) * 18 + r] = v.w;
  }
#pragma unroll
  for (int j = 0; j < 8; ++j)
    ((float4*)Ws)[tid + 256 * j] = ((const float4*)W1)[tid + 256 * j];
  __syncthreads();

  const int bt = tid >> 5, ht = tid & 31;
  float bh0 = b1[ht * 2], bh1 = b1[ht * 2 + 1];
  float a00 = bh0, a01 = bh1, a10 = bh0, a11 = bh1;
#pragma unroll 8
  for (int k = 0; k < 128; ++k) {
    float2 xv = *(const float2*)&xsT[k * 18 + bt * 2];
    float2 wv = *(const float2*)&Ws[k * 64 + ht * 2];
    a00 = fmaf(xv.x, wv.x, a00); a01 = fmaf(xv.x, wv.y, a01);
    a10 = fmaf(xv.y, wv.x, a10); a11 = fmaf(xv.y, wv.y, a11);
  }
  a00 = fmaxf(a00, 0.f); a01 = fmaxf(a01, 0.f);
  a10 = fmaxf(a10, 0.f); a11 = fmaxf(a11, 0.f);
  hids[(ht * 2 + 0) * 18 + bt * 2 + 0] = a00;
  hids[(ht * 2 + 1) * 18 + bt * 2 + 0] = a01;
  hids[(ht * 2 + 0) * 18 + bt * 2 + 1] = a10;
  hids[(ht * 2 + 1) * 18 + bt * 2 + 1] = a11;
  __syncthreads();

#pragma unroll
  for (int j = 0; j < 8; ++j)
    ((float4*)Ws)[tid + 256 * j] = ((const float4*)W2)[tid + 256 * j];
  __syncthreads();

  const int bt2 = tid >> 5, tt = tid & 31;
  float l0[4], l1[4];
#pragma unroll
  for (int j = 0; j < 4; ++j) { l0[j] = b2[tt * 4 + j]; l1[j] = l0[j]; }
#pragma unroll 4
  for (int k = 0; k < 64; ++k) {
    float2 hv = *(const float2*)&hids[k * 18 + bt2 * 2];
    float4 wv = *(const float4*)&Ws[k * 128 + tt * 4];
    float w[4] = {wv.x, wv.y, wv.z, wv.w};
#pragma unroll
    for (int j = 0; j < 4; ++j) {
      l0[j] = fmaf(hv.x, w[j], l0[j]);
      l1[j] = fmaf(hv.y, w[j], l1[j]);
    }
  }
#pragma unroll
  for (int j = 0; j < 4; ++j) {
    lgt[(bt2 * 2 + 0) * 128 + tt * 4 + j] = l0[j];
    lgt[(bt2 * 2 + 1) * 128 + tt * 4 + j] = l1[j];
  }
  __syncthreads();

  if (tid < 16) {
    float m = -1e30f;
    for (int t = 0; t < TT; ++t) m = fmaxf(m, lgt[tid * 128 + t]);
    float s = 0.f;
    for (int t = 0; t < TT; ++t) s += __expf(lgt[tid * 128 + t] - m);
    mred[tid] = m; sred[tid] = 1.f / s;
  }
  __syncthreads();

#pragma unroll
  for (int j = 0; j < 8; ++j) {
    int idx = tid + 256 * j;
    int r = idx & 15, t = idx >> 4;
    float a = __expf(lgt[r * 128 + t] - mred[r]) * sred[r];
    attnT[(size_t)t * BB + bbase + r] = a;
  }
}

// ---------------- Kernel 4: main contraction --------------------------------
// grid (16 b-groups of 512, 32 tree-groups of 4); block 256 = 4 waves.
// wave w: tree tg*4+w; lane covers 8 batches (b0 + q*64, q=0..7).
// LP staged in LDS; each broadcast b128 row read feeds 8 batches.
__global__ __launch_bounds__(256, 2) void main_kernel(
    const float* __restrict__ sT, const float* __restrict__ attnT,
    const float* __restrict__ lp, __half* __restrict__ partial) {
  __shared__ float smem[10240];  // 40KB: LP stage (6144 floats) then red (2x5120)
  const int bg = blockIdx.x, tg = blockIdx.y;
  const int tid = threadIdx.x;
  const int w = tid >> 6, ln = tid & 63;

  // stage LP for 4 trees: 6144 floats = 1536 float4
#pragma unroll
  for (int j = 0; j < 6; ++j)
    ((float4*)smem)[tid + 256 * j] =
        ((const float4*)(lp + (size_t)tg * 4 * 1536))[tid + 256 * j];
  __syncthreads();

  const int t = tg * 4 + w;
  const int b0 = bg * 512 + ln;

  // phi factors: pl (d0..2), w34 (d3,d4), w56 (d5,d6 with attn folded)
  float pl[8][8], w34[8][4], w56[8][4];
#pragma unroll
  for (int q = 0; q < 8; ++q) {
    float s0 = sT[(size_t)(t * 7 + 0) * BB + b0 + q * 64];
    float s1 = sT[(size_t)(t * 7 + 1) * BB + b0 + q * 64];
    float s2 = sT[(size_t)(t * 7 + 2) * BB + b0 + q * 64];
    float s3 = sT[(size_t)(t * 7 + 3) * BB + b0 + q * 64];
    float s4 = sT[(size_t)(t * 7 + 4) * BB + b0 + q * 64];
    float s5 = sT[(size_t)(t * 7 + 5) * BB + b0 + q * 64];
    float s6 = sT[(size_t)(t * 7 + 6) * BB + b0 + q * 64];
    float A  = attnT[(size_t)t * BB + b0 + q * 64];
    // bit d of leaf index: 0 -> s_d, 1 -> (1-s_d)
    float t01_0 = s0 * s1, t01_1 = (1.f - s0) * s1;
    float t01_2 = s0 * (1.f - s1), t01_3 = (1.f - s0) * (1.f - s1);
    float s2c = 1.f - s2;
    pl[q][0] = t01_0 * s2;  pl[q][1] = t01_1 * s2;
    pl[q][2] = t01_2 * s2;  pl[q][3] = t01_3 * s2;
    pl[q][4] = t01_0 * s2c; pl[q][5] = t01_1 * s2c;
    pl[q][6] = t01_2 * s2c; pl[q][7] = t01_3 * s2c;
    float s3c = 1.f - s3, s4c = 1.f - s4;
    w34[q][0] = s3 * s4;  w34[q][1] = s3c * s4;
    w34[q][2] = s3 * s4c; w34[q][3] = s3c * s4c;
    float as6 = A * s6, as6c = A * (1.f - s6);
    float s5c = 1.f - s5;
    w56[q][0] = s5 * as6;  w56[q][1] = s5c * as6;
    w56[q][2] = s5 * as6c; w56[q][3] = s5c * as6c;
  }

  float acc[8][10];
#pragma unroll
  for (int q = 0; q < 8; ++q)
#pragma unroll
    for (int c = 0; c < 10; ++c) acc[q][c] = 0.f;

  const float4* lpw = (const float4*)(smem + w * 1536);
#pragma unroll 1
  for (int h5 = 0; h5 < 4; ++h5) {        // h5 = hi>>2 (d5,d6) via w56[0] + rotate
    const float4* p5 = lpw + h5 * 96;     // 32 leaves * 3 float4
#pragma unroll
    for (int h3 = 0; h3 < 4; ++h3) {      // hi&3 (d3,d4)
      float ph[8];
#pragma unroll
      for (int q = 0; q < 8; ++q) ph[q] = w34[q][h3] * w56[q][0];
#pragma unroll
      for (int lo = 0; lo < 8; ++lo) {
        float4 va = p5[h3 * 24 + lo * 3 + 0];
        float4 vb = p5[h3 * 24 + lo * 3 + 1];
        float4 vc = p5[h3 * 24 + lo * 3 + 2];
#pragma unroll
        for (int q = 0; q < 8; ++q) {
          float p = pl[q][lo] * ph[q];
          acc[q][0] = fmaf(p, va.x, acc[q][0]);
          acc[q][1] = fmaf(p, va.y, acc[q][1]);
          acc[q][2] = fmaf(p, va.z, acc[q][2]);
          acc[q][3] = fmaf(p, va.w, acc[q][3]);
          acc[q][4] = fmaf(p, vb.x, acc[q][4]);
          acc[q][5] = fmaf(p, vb.y, acc[q][5]);
          acc[q][6] = fmaf(p, vb.z, acc[q][6]);
          acc[q][7] = fmaf(p, vb.w, acc[q][7]);
          acc[q][8] = fmaf(p, vc.x, acc[q][8]);
          acc[q][9] = fmaf(p, vc.y, acc[q][9]);
        }
      }
    }
    // rotate w56 left
#pragma unroll
    for (int q = 0; q < 8; ++q) {
      w56[q][0] = w56[q][1]; w56[q][1] = w56[q][2]; w56[q][2] = w56[q][3];
    }
  }

  // cross-wave tree reduction in LDS (reuse smem): red[2][512][10]
  __syncthreads();
  float* red = smem + (w & 1) * 5120;
  if (w < 2) {
#pragma unroll
    for (int q = 0; q < 8; ++q)
#pragma unroll
      for (int c = 0; c < 10; ++c) red[(q * 64 + ln) * 10 + c] = acc[q][c];
  }
  __syncthreads();
  if (w >= 2) {
#pragma unroll
    for (int q = 0; q < 8; ++q)
#pragma unroll
      for (int c = 0; c < 10; ++c) red[(q * 64 + ln) * 10 + c] += acc[q][c];
  }
  __syncthreads();

#pragma unroll
  for (int j = 0; j < 20; ++j) {
    int i = tid + 256 * j;                 // 0..5119 = bl*10+c
    float v = smem[i] + smem[5120 + i];
    partial[(size_t)tg * 81920 + (size_t)bg * 5120 + i] = __float2half(v);
  }
}

// ---------------- Kernel 5: final reduce over 32 tree-groups ----------------
__global__ __launch_bounds__(256) void reduce_kernel(
    const __half* __restrict__ partial, float* __restrict__ out) {
  int idx2 = blockIdx.x * 256 + threadIdx.x;  // 0..40959 (pairs)
  float s0 = 0.f, s1 = 0.f;
#pragma unroll
  for (int tg = 0; tg < 32; ++tg) {
    __half2 h = *(const __half2*)(partial + (size_t)tg * 81920 + idx2 * 2);
    float2 f = __half22float2(h);
    s0 += f.x; s1 += f.y;
  }
  ((float2*)out)[idx2] = make_float2(s0, s1);
}

// ---------------------------------------------------------------------------
extern "C" void kernel_launch(void* const* d_in, const int* in_sizes, int n_in,
                              void* d_out, int out_size, void* d_ws, size_t ws_size,
                              hipStream_t stream) {
  const float* x    = (const float*)d_in[0];
  const float* mask = (const float*)d_in[1];
  const float* thr  = (const float*)d_in[2];
  const float* lo   = (const float*)d_in[3];
  const float* W1   = (const float*)d_in[4];
  const float* b1   = (const float*)d_in[5];
  const float* W2   = (const float*)d_in[6];
  const float* b2   = (const float*)d_in[7];
  float* out = (float*)d_out;
  float* ws  = (float*)d_ws;

  float*  sT      = ws + OFF_S;
  float*  LPpad   = ws + OFF_LP;
  float*  attnT   = ws + OFF_AT;
  __half* partial = (__half*)(ws + OFF_PT);

  zs_kernel<<<dim3(32, 14), 256, 0, stream>>>(mask, x, thr, sT);
  leafsm_kernel<<<64, 256, 0, stream>>>(lo, LPpad);
  attn_kernel<<<512, 256, 0, stream>>>(x, W1, b1, W2, b2, attnT);
  main_kernel<<<dim3(16, 32), 256, 0, stream>>>(sT, attnT, LPpad, partial);
  reduce_kernel<<<160, 256, 0, stream>>>(partial, out);
}

// Round 4
// 140.542 us; speedup vs baseline: 1.5433x; 1.1553x over previous
//
#include <hip/hip_runtime.h>

// Problem: B=8192, T=128, D=7, I=128, C=10, H=64, L=128
// ws layout (floats):
//   sT      [896][8192]          off 0          (7,340,032)
//   attnT   [128][8192]          off 7,340,032  (1,048,576)
//   LPpad   [16384][12] f32      off 8,388,608  (196,608)
//   LPb     bf16 B-frags         off 8,585,216  (524,288 float-slots = 2MB)
//            layout: [t][slice][lane] x 4 dwords (8 bf16)
// total 9,109,504 floats = 36.4 MB (< proven 39.6 MB budget)

#define BB 8192
#define TT 128
#define II 128
#define CC 10
#define HH 64

#define OFF_S   0
#define OFF_AT  7340032
#define OFF_LPP 8388608
#define OFF_LPB 8585216

typedef __attribute__((ext_vector_type(8))) short short8;
typedef __attribute__((ext_vector_type(16))) float floatx16;

static __device__ inline unsigned short f2bf(float f) {
  unsigned int u = __float_as_uint(f);
  unsigned int r = u + 0x7FFF + ((u >> 16) & 1);   // RNE; inputs finite >=0
  return (unsigned short)(r >> 16);
}

// ---------------- Kernel 1: z GEMM + softsign, sT[td][b] (unchanged) --------
__global__ __launch_bounds__(256) void zs_kernel(
    const float* __restrict__ mask, const float* __restrict__ x,
    const float* __restrict__ thr, float* __restrict__ sT) {
  __shared__ float As[32 * 68];    // [k][m]
  __shared__ float Bs[32 * 260];   // [k][n]
  const int ng = blockIdx.x;
  const int mt = blockIdx.y;
  const int tid = threadIdx.x;
  const int tm = tid & 7;
  const int tn = tid >> 3;

  float acc[8][8];
#pragma unroll
  for (int i = 0; i < 8; ++i)
#pragma unroll
    for (int j = 0; j < 8; ++j) acc[i][j] = 0.f;

  for (int kc = 0; kc < 4; ++kc) {
    __syncthreads();
#pragma unroll
    for (int j = 0; j < 2; ++j) {
      int f = tid + 256 * j;
      int r = f >> 3, k4 = f & 7;
      float4 a = *(const float4*)(mask + (size_t)(mt * 64 + r) * II + kc * 32 + k4 * 4);
      As[(k4 * 4 + 0) * 68 + r] = a.x; As[(k4 * 4 + 1) * 68 + r] = a.y;
      As[(k4 * 4 + 2) * 68 + r] = a.z; As[(k4 * 4 + 3) * 68 + r] = a.w;
    }
#pragma unroll
    for (int j = 0; j < 8; ++j) {
      int f = tid + 256 * j;
      int r = f >> 3, k4 = f & 7;
      float4 b = *(const float4*)(x + (size_t)(ng * 256 + r) * II + kc * 32 + k4 * 4);
      Bs[(k4 * 4 + 0) * 260 + r] = b.x; Bs[(k4 * 4 + 1) * 260 + r] = b.y;
      Bs[(k4 * 4 + 2) * 260 + r] = b.z; Bs[(k4 * 4 + 3) * 260 + r] = b.w;
    }
    __syncthreads();

#pragma unroll 4
    for (int k = 0; k < 32; ++k) {
      float4 a0 = *(const float4*)&As[k * 68 + tm * 8];
      float4 a1 = *(const float4*)&As[k * 68 + tm * 8 + 4];
      float4 b0 = *(const float4*)&Bs[k * 260 + tn * 8];
      float4 b1 = *(const float4*)&Bs[k * 260 + tn * 8 + 4];
      float am[8] = {a0.x, a0.y, a0.z, a0.w, a1.x, a1.y, a1.z, a1.w};
      float bn[8] = {b0.x, b0.y, b0.z, b0.w, b1.x, b1.y, b1.z, b1.w};
#pragma unroll
      for (int i = 0; i < 8; ++i)
#pragma unroll
        for (int j = 0; j < 8; ++j) acc[i][j] = fmaf(am[i], bn[j], acc[i][j]);
    }
  }

#pragma unroll
  for (int i = 0; i < 8; ++i) {
    int m = mt * 64 + tm * 8 + i;
    float th = thr[m];
    float o[8];
#pragma unroll
    for (int j = 0; j < 8; ++j) {
      float z = acc[i][j] - th;
      o[j] = 0.5f * (z / (1.f + fabsf(z)) + 1.f);
    }
    float* dst = sT + (size_t)m * BB + ng * 256 + tn * 8;
    *(float4*)(dst) = make_float4(o[0], o[1], o[2], o[3]);
    *(float4*)(dst + 4) = make_float4(o[4], o[5], o[6], o[7]);
  }
}

// ---------------- Kernel 2: leaf softmax (+ zero out for atomics) -----------
__global__ __launch_bounds__(256) void leafsm_kernel(
    const float* __restrict__ lo, float* __restrict__ lp, float* __restrict__ out) {
  int idx = blockIdx.x * 256 + threadIdx.x;   // grid 320 blocks = 81920 threads
  if (idx < BB * CC) out[idx] = 0.f;
  if (idx < TT * 128) {
    const float* row = lo + (size_t)idx * CC;
    float v[CC];
    float m = -1e30f;
#pragma unroll
    for (int c = 0; c < CC; ++c) { v[c] = row[c]; m = fmaxf(m, v[c]); }
    float s = 0.f;
#pragma unroll
    for (int c = 0; c < CC; ++c) { v[c] = __expf(v[c] - m); s += v[c]; }
    float inv = 1.f / s;
    float* o = lp + (size_t)idx * 12;
#pragma unroll
    for (int c = 0; c < CC; ++c) o[c] = v[c] * inv;
    o[10] = 0.f; o[11] = 0.f;
  }
}

// ---------------- Kernel 2b: pack LP into MFMA B-fragment layout (bf16) -----
// B-frag for 32x32x16: lane holds B[k=(lane>>5)*8+j][n=lane&31], j=0..7.
// k = leaf within slice of 16; leaf l = slice*16 + (lane>>5)*8 + j; n = c.
__global__ __launch_bounds__(256) void pack_kernel(
    const float* __restrict__ lp, unsigned int* __restrict__ lpb) {
  int idx = blockIdx.x * 256 + threadIdx.x;   // 0..65535 = (t, s, lane)
  int t = idx >> 9, rem = idx & 511;
  int s = rem >> 6, lane = rem & 63;
  int half = lane >> 5, n = lane & 31;
  unsigned int w[4];
#pragma unroll
  for (int jp = 0; jp < 4; ++jp) {
    int l0 = s * 16 + half * 8 + jp * 2;
    float f0 = (n < CC) ? lp[(size_t)(t * 128 + l0) * 12 + n] : 0.f;
    float f1 = (n < CC) ? lp[(size_t)(t * 128 + l0 + 1) * 12 + n] : 0.f;
    w[jp] = (unsigned int)f2bf(f0) | ((unsigned int)f2bf(f1) << 16);
  }
  ((uint4*)lpb)[idx] = make_uint4(w[0], w[1], w[2], w[3]);
}

// ---------------- Kernel 3: fused attention MLP + softmax (unchanged) -------
__global__ __launch_bounds__(256) void attn_kernel(
    const float* __restrict__ x, const float* __restrict__ W1,
    const float* __restrict__ b1, const float* __restrict__ W2,
    const float* __restrict__ b2, float* __restrict__ attnT) {
  __shared__ float xsT[128 * 18];
  __shared__ float Ws[8192];
  __shared__ float hids[64 * 18];
  __shared__ float lgt[16 * 128];
  __shared__ float mred[16], sred[16];
  const int tid = threadIdx.x;
  const int bbase = blockIdx.x * 16;

#pragma unroll
  for (int j = 0; j < 2; ++j) {
    int f = tid + 256 * j;
    int r = f >> 5, k4 = f & 31;
    float4 v = *(const float4*)(x + (size_t)(bbase + r) * II + k4 * 4);
    xsT[(k4 * 4 + 0) * 18 + r] = v.x; xsT[(k4 * 4 + 1) * 18 + r] = v.y;
    xsT[(k4 * 4 + 2) * 18 + r] = v.z; xsT[(k4 * 4 + 3) * 18 + r] = v.w;
  }
#pragma unroll
  for (int j = 0; j < 8; ++j)
    ((float4*)Ws)[tid + 256 * j] = ((const float4*)W1)[tid + 256 * j];
  __syncthreads();

  const int bt = tid >> 5, ht = tid & 31;
  float bh0 = b1[ht * 2], bh1 = b1[ht * 2 + 1];
  float a00 = bh0, a01 = bh1, a10 = bh0, a11 = bh1;
#pragma unroll 8
  for (int k = 0; k < 128; ++k) {
    float2 xv = *(const float2*)&xsT[k * 18 + bt * 2];
    float2 wv = *(const float2*)&Ws[k * 64 + ht * 2];
    a00 = fmaf(xv.x, wv.x, a00); a01 = fmaf(xv.x, wv.y, a01);
    a10 = fmaf(xv.y, wv.x, a10); a11 = fmaf(xv.y, wv.y, a11);
  }
  a00 = fmaxf(a00, 0.f); a01 = fmaxf(a01, 0.f);
  a10 = fmaxf(a10, 0.f); a11 = fmaxf(a11, 0.f);
  hids[(ht * 2 + 0) * 18 + bt * 2 + 0] = a00;
  hids[(ht * 2 + 1) * 18 + bt * 2 + 0] = a01;
  hids[(ht * 2 + 0) * 18 + bt * 2 + 1] = a10;
  hids[(ht * 2 + 1) * 18 + bt * 2 + 1] = a11;
  __syncthreads();

#pragma unroll
  for (int j = 0; j < 8; ++j)
    ((float4*)Ws)[tid + 256 * j] = ((const float4*)W2)[tid + 256 * j];
  __syncthreads();

  const int bt2 = tid >> 5, tt = tid & 31;
  float l0[4], l1[4];
#pragma unroll
  for (int j = 0; j < 4; ++j) { l0[j] = b2[tt * 4 + j]; l1[j] = l0[j]; }
#pragma unroll 4
  for (int k = 0; k < 64; ++k) {
    float2 hv = *(const float2*)&hids[k * 18 + bt2 * 2];
    float4 wv = *(const float4*)&Ws[k * 128 + tt * 4];
    float w[4] = {wv.x, wv.y, wv.z, wv.w};
#pragma unroll
    for (int j = 0; j < 4; ++j) {
      l0[j] = fmaf(hv.x, w[j], l0[j]);
      l1[j] = fmaf(hv.y, w[j], l1[j]);
    }
  }
#pragma unroll
  for (int j = 0; j < 4; ++j) {
    lgt[(bt2 * 2 + 0) * 128 + tt * 4 + j] = l0[j];
    lgt[(bt2 * 2 + 1) * 128 + tt * 4 + j] = l1[j];
  }
  __syncthreads();

  if (tid < 16) {
    float m = -1e30f;
    for (int t = 0; t < TT; ++t) m = fmaxf(m, lgt[tid * 128 + t]);
    float s = 0.f;
    for (int t = 0; t < TT; ++t) s += __expf(lgt[tid * 128 + t] - m);
    mred[tid] = m; sred[tid] = 1.f / s;
  }
  __syncthreads();

#pragma unroll
  for (int j = 0; j < 8; ++j) {
    int idx = tid + 256 * j;
    int r = idx & 15, t = idx >> 4;
    float a = __expf(lgt[r * 128 + t] - mred[r]) * sred[r];
    attnT[(size_t)t * BB + bbase + r] = a;
  }
}

// ---------------- Kernel 4: main contraction via MFMA -----------------------
// grid (64 bg of 128 b, 16 tg of 8 trees); block 256 = 4 waves.
// wave w: rows b = bg*128 + w*32 + (lane&31); per tree: A-frag = attn-scaled
// leaf probs (bf16), B-frag = packed LP; acc fp32 in AGPRs across 8 trees.
// Leaf bits: bit d of l: 0 -> s_d, 1 -> (1-s_d).
// l = slice*16 + half*8 + j  (j=bits0-2, half=bit3, slice=bits4-6).
__global__ __launch_bounds__(256, 4) void main_kernel(
    const float* __restrict__ sT, const float* __restrict__ attnT,
    const unsigned int* __restrict__ lpb, float* __restrict__ out) {
  __shared__ float red[128 * 10];
  const int bg = blockIdx.x, tg = blockIdx.y;
  const int tid = threadIdx.x;
  const int w = tid >> 6, lane = tid & 63;
  const int half = lane >> 5;
  const int b = bg * 128 + w * 32 + (lane & 31);

  floatx16 acc;
#pragma unroll
  for (int i = 0; i < 16; ++i) acc[i] = 0.f;

#pragma unroll 1
  for (int it = 0; it < 8; ++it) {
    const int t = tg * 8 + it;
    // B-fragments: 8 slices, coalesced dwordx4 per lane
    uint4 bf[8];
    const uint4* lpt = (const uint4*)lpb + (size_t)t * 512 + lane;
#pragma unroll
    for (int s = 0; s < 8; ++s) bf[s] = lpt[s * 64];

    const float* sp = sT + (size_t)t * 7 * BB + b;
    float s0 = sp[0 * BB], s1 = sp[1 * BB], s2 = sp[2 * BB], s3 = sp[3 * BB];
    float s4 = sp[4 * BB], s5 = sp[5 * BB], s6 = sp[6 * BB];
    float A = attnT[(size_t)t * BB + b];

    // pl[j] over d0..2
    float s0c = 1.f - s0, s1c = 1.f - s1, s2c = 1.f - s2;
    float t0 = s0 * s1, t1 = s0c * s1, t2 = s0 * s1c, t3 = s0c * s1c;
    float pl[8];
    pl[0] = t0 * s2;  pl[1] = t1 * s2;  pl[2] = t2 * s2;  pl[3] = t3 * s2;
    pl[4] = t0 * s2c; pl[5] = t1 * s2c; pl[6] = t2 * s2c; pl[7] = t3 * s2c;
    // w[slice] over d4..6, with attn and half-sel(d3) folded in
    float sel3 = half ? (1.f - s3) : s3;
    float Af = A * sel3;
    float s4c = 1.f - s4, s5c = 1.f - s5;
    float as6 = Af * s6, as6c = Af * (1.f - s6);
    float u0 = s4 * s5, u1 = s4c * s5, u2 = s4 * s5c, u3 = s4c * s5c;
    float wv[8];
    wv[0] = u0 * as6;  wv[1] = u1 * as6;  wv[2] = u2 * as6;  wv[3] = u3 * as6;
    wv[4] = u0 * as6c; wv[5] = u1 * as6c; wv[6] = u2 * as6c; wv[7] = u3 * as6c;

#pragma unroll
    for (int s = 0; s < 8; ++s) {
      float ws = wv[s];
      union { short8 v; unsigned int u[4]; } a;
#pragma unroll
      for (int jp = 0; jp < 4; ++jp) {
        a.u[jp] = (unsigned int)f2bf(pl[jp * 2] * ws) |
                  ((unsigned int)f2bf(pl[jp * 2 + 1] * ws) << 16);
      }
      acc = __builtin_amdgcn_mfma_f32_32x32x16_bf16(
          a.v, *(const short8*)&bf[s], acc, 0, 0, 0);
    }
  }

  // epilogue: C/D layout col=lane&31 (c), row=(reg&3)+8*(reg>>2)+4*half (b)
  const int col = lane & 31;
  if (col < CC) {
#pragma unroll
    for (int r = 0; r < 16; ++r) {
      int row = (r & 3) + 8 * (r >> 2) + 4 * half;
      red[(w * 32 + row) * 10 + col] = acc[r];
    }
  }
  __syncthreads();
#pragma unroll
  for (int j = 0; j < 5; ++j) {
    int idx = tid + 256 * j;   // 0..1279
    atomicAdd(out + (size_t)bg * 1280 + idx, red[idx]);
  }
}

// ---------------------------------------------------------------------------
extern "C" void kernel_launch(void* const* d_in, const int* in_sizes, int n_in,
                              void* d_out, int out_size, void* d_ws, size_t ws_size,
                              hipStream_t stream) {
  const float* x    = (const float*)d_in[0];
  const float* mask = (const float*)d_in[1];
  const float* thr  = (const float*)d_in[2];
  const float* lo   = (const float*)d_in[3];
  const float* W1   = (const float*)d_in[4];
  const float* b1   = (const float*)d_in[5];
  const float* W2   = (const float*)d_in[6];
  const float* b2   = (const float*)d_in[7];
  float* out = (float*)d_out;
  float* ws  = (float*)d_ws;

  float*        sT    = ws + OFF_S;
  float*        attnT = ws + OFF_AT;
  float*        LPpad = ws + OFF_LPP;
  unsigned int* LPb   = (unsigned int*)(ws + OFF_LPB);

  zs_kernel<<<dim3(32, 14), 256, 0, stream>>>(mask, x, thr, sT);
  leafsm_kernel<<<320, 256, 0, stream>>>(lo, LPpad, out);
  pack_kernel<<<256, 256, 0, stream>>>(LPpad, LPb);
  attn_kernel<<<512, 256, 0, stream>>>(x, W1, b1, W2, b2, attnT);
  main_kernel<<<dim3(64, 16), 256, 0, stream>>>(sT, attnT, LPb, out);
}

// Round 5
// 137.732 us; speedup vs baseline: 1.5747x; 1.0204x over previous
//
#include <hip/hip_runtime.h>
#include <hip/hip_bf16.h>

// Problem: B=8192, T=128, D=7, I=128, C=10, H=64, L=128
// ws layout (floats):
//   sT      [896][8192]      off 0          (7,340,032)
//   attnT   [128][8192]      off 7,340,032  (1,048,576)
//   LPb     bf16 B-frags     off 8,388,608  (262,144 float-slots = 1MB)
//            layout: [t][slice][lane] as uint4 (8 bf16)
//   partial [16][8192][10]   off 8,650,752  (1,310,720)
// total 9,961,472 floats = 39.85 MB

#define BB 8192
#define TT 128
#define II 128
#define CC 10
#define HH 64

#define OFF_S   0
#define OFF_AT  7340032
#define OFF_LPB 8388608
#define OFF_PT  8650752

typedef __attribute__((ext_vector_type(8))) short short8;
typedef __attribute__((ext_vector_type(16))) float floatx16;

static __device__ inline unsigned short f2bf(float f) {
  unsigned int u = __float_as_uint(f);
  unsigned int r = u + 0x7FFF + ((u >> 16) & 1);   // RNE
  return (unsigned short)(r >> 16);
}

static __device__ inline unsigned int pkbf(float lo, float hi) {
  __hip_bfloat162 h = __float22bfloat162_rn(make_float2(lo, hi));
  unsigned int u;
  __builtin_memcpy(&u, &h, 4);
  return u;
}

static __device__ inline short8 cvt8(float4 a, float4 b) {
  union { short8 v; unsigned int u[4]; } r;
  r.u[0] = pkbf(a.x, a.y);
  r.u[1] = pkbf(a.z, a.w);
  r.u[2] = pkbf(b.x, b.y);
  r.u[3] = pkbf(b.z, b.w);
  return r.v;
}

// ---------------- Kernel 1: z GEMM via MFMA bf16 + softsign, sT[td][b] ------
// grid (28 m-blocks of 32 td, 32 n-supers of 256 b); block 256 = 4 waves.
// No LDS: A (mask) and B (x) fragments are 8 consecutive floats -> direct
// global dwordx4 loads + packed bf16 cvt. A-frags+thr cached in registers.
__global__ __launch_bounds__(256, 4) void zs_kernel(
    const float* __restrict__ mask, const float* __restrict__ x,
    const float* __restrict__ thr, float* __restrict__ sT) {
  const int mb = blockIdx.x;      // 32 td
  const int ns = blockIdx.y;      // 256 b
  const int w = threadIdx.x >> 6, lane = threadIdx.x & 63;
  const int half = lane >> 5, l31 = lane & 31;
  const int m0 = mb * 32;

  // A-frags: mask[m0+l31][16*s + half*8 + j], j=0..7
  short8 af[8];
  const float* mrow = mask + (size_t)(m0 + l31) * II + half * 8;
#pragma unroll
  for (int s = 0; s < 8; ++s) {
    float4 a = *(const float4*)(mrow + s * 16);
    float4 b = *(const float4*)(mrow + s * 16 + 4);
    af[s] = cvt8(a, b);
  }
  // thresholds for this lane's 16 C-rows
  float th[16];
#pragma unroll
  for (int r = 0; r < 16; ++r)
    th[r] = thr[m0 + (r & 3) + 8 * (r >> 2) + 4 * half];

#pragma unroll
  for (int nb = 0; nb < 2; ++nb) {
    const int n0 = ns * 256 + w * 64 + nb * 32;
    const float* xrow = x + (size_t)(n0 + l31) * II + half * 8;
    floatx16 acc;
#pragma unroll
    for (int i = 0; i < 16; ++i) acc[i] = 0.f;
#pragma unroll
    for (int s = 0; s < 8; ++s) {
      float4 a = *(const float4*)(xrow + s * 16);
      float4 b = *(const float4*)(xrow + s * 16 + 4);
      short8 bf = cvt8(a, b);
      acc = __builtin_amdgcn_mfma_f32_32x32x16_bf16(af[s], bf, acc, 0, 0, 0);
    }
#pragma unroll
    for (int r = 0; r < 16; ++r) {
      int row = (r & 3) + 8 * (r >> 2) + 4 * half;
      float z = acc[r] - th[r];
      float o = 0.5f * (z / (1.f + fabsf(z)) + 1.f);
      sT[(size_t)(m0 + row) * BB + n0 + l31] = o;
    }
  }
}

// ---------------- Kernel 2: leaf softmax + pack B-frags (fused) -------------
// block = 2 trees x 128 leaves; softmax -> LDS -> pack to MFMA B layout.
// B-frag: lane holds B[k=(lane>>5)*8+j][n=lane&31]; leaf l = s*16+(lane>>5)*8+j.
__global__ __launch_bounds__(256) void prep_kernel(
    const float* __restrict__ lo, unsigned int* __restrict__ lpb) {
  __shared__ float lps[2 * 128 * 12];   // 12 KB
  const int tid = threadIdx.x;
  const int t0 = blockIdx.x * 2;        // grid 64

  {
    int tl = tid >> 7, l = tid & 127;
    const float* row = lo + ((size_t)(t0 + tl) * 128 + l) * CC;
    float v[CC];
    float m = -1e30f;
#pragma unroll
    for (int c = 0; c < CC; ++c) { v[c] = row[c]; m = fmaxf(m, v[c]); }
    float s = 0.f;
#pragma unroll
    for (int c = 0; c < CC; ++c) { v[c] = __expf(v[c] - m); s += v[c]; }
    float inv = 1.f / s;
    float* o = lps + (tl * 128 + l) * 12;
#pragma unroll
    for (int c = 0; c < CC; ++c) o[c] = v[c] * inv;
    o[10] = 0.f; o[11] = 0.f;
  }
  __syncthreads();

#pragma unroll
  for (int jj = 0; jj < 4; ++jj) {
    int idx = tid + 256 * jj;           // 0..1023 = (tl, s, lane)
    int tl = idx >> 9, rem = idx & 511;
    int s = rem >> 6, lane = rem & 63;
    int hf = lane >> 5, n = lane & 31;
    unsigned int wd[4];
#pragma unroll
    for (int jp = 0; jp < 4; ++jp) {
      int l0 = s * 16 + hf * 8 + jp * 2;
      float f0 = (n < CC) ? lps[(tl * 128 + l0) * 12 + n] : 0.f;
      float f1 = (n < CC) ? lps[(tl * 128 + l0 + 1) * 12 + n] : 0.f;
      wd[jp] = (unsigned int)f2bf(f0) | ((unsigned int)f2bf(f1) << 16);
    }
    ((uint4*)lpb)[(size_t)(t0 + tl) * 512 + s * 64 + lane] =
        make_uint4(wd[0], wd[1], wd[2], wd[3]);
  }
}

// ---------------- Kernel 3: fused attention MLP + softmax (unchanged) -------
__global__ __launch_bounds__(256) void attn_kernel(
    const float* __restrict__ x, const float* __restrict__ W1,
    const float* __restrict__ b1, const float* __restrict__ W2,
    const float* __restrict__ b2, float* __restrict__ attnT) {
  __shared__ float xsT[128 * 18];
  __shared__ float Ws[8192];
  __shared__ float hids[64 * 18];
  __shared__ float lgt[16 * 128];
  __shared__ float mred[16], sred[16];
  const int tid = threadIdx.x;
  const int bbase = blockIdx.x * 16;

#pragma unroll
  for (int j = 0; j < 2; ++j) {
    int f = tid + 256 * j;
    int r = f >> 5, k4 = f & 31;
    float4 v = *(const float4*)(x + (size_t)(bbase + r) * II + k4 * 4);
    xsT[(k4 * 4 + 0) * 18 + r] = v.x; xsT[(k4 * 4 + 1) * 18 + r] = v.y;
    xsT[(k4 * 4 + 2) * 18 + r] = v.z; xsT[(k4 * 4 + 3) * 18 + r] = v.w;
  }
#pragma unroll
  for (int j = 0; j < 8; ++j)
    ((float4*)Ws)[tid + 256 * j] = ((const float4*)W1)[tid + 256 * j];
  __syncthreads();

  const int bt = tid >> 5, ht = tid & 31;
  float bh0 = b1[ht * 2], bh1 = b1[ht * 2 + 1];
  float a00 = bh0, a01 = bh1, a10 = bh0, a11 = bh1;
#pragma unroll 8
  for (int k = 0; k < 128; ++k) {
    float2 xv = *(const float2*)&xsT[k * 18 + bt * 2];
    float2 wv = *(const float2*)&Ws[k * 64 + ht * 2];
    a00 = fmaf(xv.x, wv.x, a00); a01 = fmaf(xv.x, wv.y, a01);
    a10 = fmaf(xv.y, wv.x, a10); a11 = fmaf(xv.y, wv.y, a11);
  }
  a00 = fmaxf(a00, 0.f); a01 = fmaxf(a01, 0.f);
  a10 = fmaxf(a10, 0.f); a11 = fmaxf(a11, 0.f);
  hids[(ht * 2 + 0) * 18 + bt * 2 + 0] = a00;
  hids[(ht * 2 + 1) * 18 + bt * 2 + 0] = a01;
  hids[(ht * 2 + 0) * 18 + bt * 2 + 1] = a10;
  hids[(ht * 2 + 1) * 18 + bt * 2 + 1] = a11;
  __syncthreads();

#pragma unroll
  for (int j = 0; j < 8; ++j)
    ((float4*)Ws)[tid + 256 * j] = ((const float4*)W2)[tid + 256 * j];
  __syncthreads();

  const int bt2 = tid >> 5, tt = tid & 31;
  float l0[4], l1[4];
#pragma unroll
  for (int j = 0; j < 4; ++j) { l0[j] = b2[tt * 4 + j]; l1[j] = l0[j]; }
#pragma unroll 4
  for (int k = 0; k < 64; ++k) {
    float2 hv = *(const float2*)&hids[k * 18 + bt2 * 2];
    float4 wv = *(const float4*)&Ws[k * 128 + tt * 4];
    float w[4] = {wv.x, wv.y, wv.z, wv.w};
#pragma unroll
    for (int j = 0; j < 4; ++j) {
      l0[j] = fmaf(hv.x, w[j], l0[j]);
      l1[j] = fmaf(hv.y, w[j], l1[j]);
    }
  }
#pragma unroll
  for (int j = 0; j < 4; ++j) {
    lgt[(bt2 * 2 + 0) * 128 + tt * 4 + j] = l0[j];
    lgt[(bt2 * 2 + 1) * 128 + tt * 4 + j] = l1[j];
  }
  __syncthreads();

  if (tid < 16) {
    float m = -1e30f;
    for (int t = 0; t < TT; ++t) m = fmaxf(m, lgt[tid * 128 + t]);
    float s = 0.f;
    for (int t = 0; t < TT; ++t) s += __expf(lgt[tid * 128 + t] - m);
    mred[tid] = m; sred[tid] = 1.f / s;
  }
  __syncthreads();

#pragma unroll
  for (int j = 0; j < 8; ++j) {
    int idx = tid + 256 * j;
    int r = idx & 15, t = idx >> 4;
    float a = __expf(lgt[r * 128 + t] - mred[r]) * sred[r];
    attnT[(size_t)t * BB + bbase + r] = a;
  }
}

// ---------------- Kernel 4: main contraction via MFMA -----------------------
// grid (64 bg of 128 b, 16 tg of 8 trees); block 256 = 4 waves.
// Epilogue: plain stores to partial (no atomics).
__global__ __launch_bounds__(256, 4) void main_kernel(
    const float* __restrict__ sT, const float* __restrict__ attnT,
    const unsigned int* __restrict__ lpb, float* __restrict__ partial) {
  __shared__ float red[128 * 10];
  const int bg = blockIdx.x, tg = blockIdx.y;
  const int tid = threadIdx.x;
  const int w = tid >> 6, lane = tid & 63;
  const int half = lane >> 5;
  const int b = bg * 128 + w * 32 + (lane & 31);

  floatx16 acc;
#pragma unroll
  for (int i = 0; i < 16; ++i) acc[i] = 0.f;

#pragma unroll 1
  for (int it = 0; it < 8; ++it) {
    const int t = tg * 8 + it;
    uint4 bf[8];
    const uint4* lpt = (const uint4*)lpb + (size_t)t * 512 + lane;
#pragma unroll
    for (int s = 0; s < 8; ++s) bf[s] = lpt[s * 64];

    const float* sp = sT + (size_t)t * 7 * BB + b;
    float s0 = sp[0 * BB], s1 = sp[1 * BB], s2 = sp[2 * BB], s3 = sp[3 * BB];
    float s4 = sp[4 * BB], s5 = sp[5 * BB], s6 = sp[6 * BB];
    float A = attnT[(size_t)t * BB + b];

    float s0c = 1.f - s0, s1c = 1.f - s1, s2c = 1.f - s2;
    float t0 = s0 * s1, t1 = s0c * s1, t2 = s0 * s1c, t3 = s0c * s1c;
    float pl[8];
    pl[0] = t0 * s2;  pl[1] = t1 * s2;  pl[2] = t2 * s2;  pl[3] = t3 * s2;
    pl[4] = t0 * s2c; pl[5] = t1 * s2c; pl[6] = t2 * s2c; pl[7] = t3 * s2c;
    float sel3 = half ? (1.f - s3) : s3;
    float Af = A * sel3;
    float s4c = 1.f - s4, s5c = 1.f - s5;
    float as6 = Af * s6, as6c = Af * (1.f - s6);
    float u0 = s4 * s5, u1 = s4c * s5, u2 = s4 * s5c, u3 = s4c * s5c;
    float wv[8];
    wv[0] = u0 * as6;  wv[1] = u1 * as6;  wv[2] = u2 * as6;  wv[3] = u3 * as6;
    wv[4] = u0 * as6c; wv[5] = u1 * as6c; wv[6] = u2 * as6c; wv[7] = u3 * as6c;

#pragma unroll
    for (int s = 0; s < 8; ++s) {
      float ws = wv[s];
      union { short8 v; unsigned int u[4]; } a;
#pragma unroll
      for (int jp = 0; jp < 4; ++jp) {
        a.u[jp] = (unsigned int)f2bf(pl[jp * 2] * ws) |
                  ((unsigned int)f2bf(pl[jp * 2 + 1] * ws) << 16);
      }
      acc = __builtin_amdgcn_mfma_f32_32x32x16_bf16(
          a.v, *(const short8*)&bf[s], acc, 0, 0, 0);
    }
  }

  const int col = lane & 31;
  if (col < CC) {
#pragma unroll
    for (int r = 0; r < 16; ++r) {
      int row = (r & 3) + 8 * (r >> 2) + 4 * half;
      red[(w * 32 + row) * 10 + col] = acc[r];
    }
  }
  __syncthreads();
#pragma unroll
  for (int j = 0; j < 5; ++j) {
    int idx = tid + 256 * j;   // 0..1279
    partial[(size_t)tg * 81920 + (size_t)bg * 1280 + idx] = red[idx];
  }
}

// ---------------- Kernel 5: final reduce over 16 tree-groups ----------------
__global__ __launch_bounds__(256) void reduce_kernel(
    const float* __restrict__ partial, float* __restrict__ out) {
  int idx = blockIdx.x * 256 + threadIdx.x;  // 0..81919
  float s = 0.f;
#pragma unroll
  for (int tg = 0; tg < 16; ++tg) s += partial[(size_t)tg * 81920 + idx];
  out[idx] = s;
}

// ---------------------------------------------------------------------------
extern "C" void kernel_launch(void* const* d_in, const int* in_sizes, int n_in,
                              void* d_out, int out_size, void* d_ws, size_t ws_size,
                              hipStream_t stream) {
  const float* x    = (const float*)d_in[0];
  const float* mask = (const float*)d_in[1];
  const float* thr  = (const float*)d_in[2];
  const float* lo   = (const float*)d_in[3];
  const float* W1   = (const float*)d_in[4];
  const float* b1   = (const float*)d_in[5];
  const float* W2   = (const float*)d_in[6];
  const float* b2   = (const float*)d_in[7];
  float* out = (float*)d_out;
  float* ws  = (float*)d_ws;

  float*        sT      = ws + OFF_S;
  float*        attnT   = ws + OFF_AT;
  unsigned int* LPb     = (unsigned int*)(ws + OFF_LPB);
  float*        partial = ws + OFF_PT;

  zs_kernel<<<dim3(28, 32), 256, 0, stream>>>(mask, x, thr, sT);
  prep_kernel<<<64, 256, 0, stream>>>(lo, LPb);
  attn_kernel<<<512, 256, 0, stream>>>(x, W1, b1, W2, b2, attnT);
  main_kernel<<<dim3(64, 16), 256, 0, stream>>>(sT, attnT, LPb, partial);
  reduce_kernel<<<320, 256, 0, stream>>>(partial, out);
}

// Round 6
// 125.110 us; speedup vs baseline: 1.7336x; 1.1009x over previous
//
#include <hip/hip_runtime.h>
#include <hip/hip_bf16.h>

// Problem: B=8192, T=128, D=7, I=128, C=10, H=64, L=128
// ws layout (floats):
//   sT      [896][8192]      off 0          (7,340,032)
//   attnT   [128][8192]      off 7,340,032  (1,048,576)
//   LPb     bf16 B-frags     off 8,388,608  (262,144 float-slots = 1MB)
//   partial [16][8192][10]   off 8,650,752  (1,310,720)
// total 9,961,472 floats = 39.85 MB

#define BB 8192
#define TT 128
#define II 128
#define CC 10
#define HH 64

#define OFF_S   0
#define OFF_AT  7340032
#define OFF_LPB 8388608
#define OFF_PT  8650752

typedef __attribute__((ext_vector_type(8))) short short8;
typedef __attribute__((ext_vector_type(16))) float floatx16;

static __device__ inline unsigned int pkbf(float lo, float hi) {
  __hip_bfloat162 h = __float22bfloat162_rn(make_float2(lo, hi));
  unsigned int u;
  __builtin_memcpy(&u, &h, 4);
  return u;
}

static __device__ inline short8 cvt8(float4 a, float4 b) {
  union { short8 v; unsigned int u[4]; } r;
  r.u[0] = pkbf(a.x, a.y);
  r.u[1] = pkbf(a.z, a.w);
  r.u[2] = pkbf(b.x, b.y);
  r.u[3] = pkbf(b.z, b.w);
  return r.v;
}

// ---------------- Phase 1: fused zs (MFMA) + prep + attn --------------------
// blocks [0,512): attn  | [512,1408): zs | [1408,1472): prep
__global__ __launch_bounds__(256, 2) void phase1_kernel(
    const float* __restrict__ x, const float* __restrict__ mask,
    const float* __restrict__ thr, const float* __restrict__ lo,
    const float* __restrict__ W1, const float* __restrict__ b1,
    const float* __restrict__ W2, const float* __restrict__ b2,
    float* __restrict__ sT, float* __restrict__ attnT,
    unsigned int* __restrict__ lpb) {
  __shared__ float smem[13728];   // 54.9 KB, partitioned per branch
  const int blk = blockIdx.x;
  const int tid = threadIdx.x;

  if (blk < 512) {
    // ---------------- attn branch ----------------
    float* xsT  = smem;            // 128*18 = 2304
    float* Ws   = smem + 2304;     // 8192
    float* hids = smem + 10496;    // 64*18 = 1152
    float* lgt  = smem + 11648;    // 2048
    float* mred = smem + 13696;    // 16
    float* sred = smem + 13712;    // 16
    const int bbase = blk * 16;

#pragma unroll
    for (int j = 0; j < 2; ++j) {
      int f = tid + 256 * j;
      int r = f >> 5, k4 = f & 31;
      float4 v = *(const float4*)(x + (size_t)(bbase + r) * II + k4 * 4);
      xsT[(k4 * 4 + 0) * 18 + r] = v.x; xsT[(k4 * 4 + 1) * 18 + r] = v.y;
      xsT[(k4 * 4 + 2) * 18 + r] = v.z; xsT[(k4 * 4 + 3) * 18 + r] = v.w;
    }
#pragma unroll
    for (int j = 0; j < 8; ++j)
      ((float4*)Ws)[tid + 256 * j] = ((const float4*)W1)[tid + 256 * j];
    __syncthreads();

    const int bt = tid >> 5, ht = tid & 31;
    float bh0 = b1[ht * 2], bh1 = b1[ht * 2 + 1];
    float a00 = bh0, a01 = bh1, a10 = bh0, a11 = bh1;
#pragma unroll 8
    for (int k = 0; k < 128; ++k) {
      float2 xv = *(const float2*)&xsT[k * 18 + bt * 2];
      float2 wv = *(const float2*)&Ws[k * 64 + ht * 2];
      a00 = fmaf(xv.x, wv.x, a00); a01 = fmaf(xv.x, wv.y, a01);
      a10 = fmaf(xv.y, wv.x, a10); a11 = fmaf(xv.y, wv.y, a11);
    }
    a00 = fmaxf(a00, 0.f); a01 = fmaxf(a01, 0.f);
    a10 = fmaxf(a10, 0.f); a11 = fmaxf(a11, 0.f);
    hids[(ht * 2 + 0) * 18 + bt * 2 + 0] = a00;
    hids[(ht * 2 + 1) * 18 + bt * 2 + 0] = a01;
    hids[(ht * 2 + 0) * 18 + bt * 2 + 1] = a10;
    hids[(ht * 2 + 1) * 18 + bt * 2 + 1] = a11;
    __syncthreads();

#pragma unroll
    for (int j = 0; j < 8; ++j)
      ((float4*)Ws)[tid + 256 * j] = ((const float4*)W2)[tid + 256 * j];
    __syncthreads();

    const int bt2 = tid >> 5, tt = tid & 31;
    float l0[4], l1[4];
#pragma unroll
    for (int j = 0; j < 4; ++j) { l0[j] = b2[tt * 4 + j]; l1[j] = l0[j]; }
#pragma unroll 4
    for (int k = 0; k < 64; ++k) {
      float2 hv = *(const float2*)&hids[k * 18 + bt2 * 2];
      float4 wv = *(const float4*)&Ws[k * 128 + tt * 4];
      float w[4] = {wv.x, wv.y, wv.z, wv.w};
#pragma unroll
      for (int j = 0; j < 4; ++j) {
        l0[j] = fmaf(hv.x, w[j], l0[j]);
        l1[j] = fmaf(hv.y, w[j], l1[j]);
      }
    }
#pragma unroll
    for (int j = 0; j < 4; ++j) {
      lgt[(bt2 * 2 + 0) * 128 + tt * 4 + j] = l0[j];
      lgt[(bt2 * 2 + 1) * 128 + tt * 4 + j] = l1[j];
    }
    __syncthreads();

    if (tid < 16) {
      float m = -1e30f;
      for (int t = 0; t < TT; ++t) m = fmaxf(m, lgt[tid * 128 + t]);
      float s = 0.f;
      for (int t = 0; t < TT; ++t) s += __expf(lgt[tid * 128 + t] - m);
      mred[tid] = m; sred[tid] = 1.f / s;
    }
    __syncthreads();

#pragma unroll
    for (int j = 0; j < 8; ++j) {
      int idx = tid + 256 * j;
      int r = idx & 15, t = idx >> 4;
      float a = __expf(lgt[r * 128 + t] - mred[r]) * sred[r];
      attnT[(size_t)t * BB + bbase + r] = a;
    }

  } else if (blk < 1408) {
    // ---------------- zs branch (MFMA, no LDS) ----------------
    const int blk2 = blk - 512;
    const int mb = blk2 >> 5;       // 0..27
    const int ns = blk2 & 31;       // 0..31
    const int w = tid >> 6, lane = tid & 63;
    const int half = lane >> 5, l31 = lane & 31;
    const int m0 = mb * 32;

    short8 af[8];
    const float* mrow = mask + (size_t)(m0 + l31) * II + half * 8;
#pragma unroll
    for (int s = 0; s < 8; ++s) {
      float4 a = *(const float4*)(mrow + s * 16);
      float4 b = *(const float4*)(mrow + s * 16 + 4);
      af[s] = cvt8(a, b);
    }
    float th[16];
#pragma unroll
    for (int r = 0; r < 16; ++r)
      th[r] = thr[m0 + (r & 3) + 8 * (r >> 2) + 4 * half];

#pragma unroll
    for (int nb = 0; nb < 2; ++nb) {
      const int n0 = ns * 256 + w * 64 + nb * 32;
      const float* xrow = x + (size_t)(n0 + l31) * II + half * 8;
      floatx16 acc;
#pragma unroll
      for (int i = 0; i < 16; ++i) acc[i] = 0.f;
#pragma unroll
      for (int s = 0; s < 8; ++s) {
        float4 a = *(const float4*)(xrow + s * 16);
        float4 b = *(const float4*)(xrow + s * 16 + 4);
        short8 bf = cvt8(a, b);
        acc = __builtin_amdgcn_mfma_f32_32x32x16_bf16(af[s], bf, acc, 0, 0, 0);
      }
#pragma unroll
      for (int r = 0; r < 16; ++r) {
        int row = (r & 3) + 8 * (r >> 2) + 4 * half;
        float z = acc[r] - th[r];
        float o = 0.5f * (z / (1.f + fabsf(z)) + 1.f);
        sT[(size_t)(m0 + row) * BB + n0 + l31] = o;
      }
    }

  } else {
    // ---------------- prep branch ----------------
    float* lps = smem;   // 2*128*12 = 3072
    const int t0 = (blk - 1408) * 2;
    {
      int tl = tid >> 7, l = tid & 127;
      const float* row = lo + ((size_t)(t0 + tl) * 128 + l) * CC;
      float v[CC];
      float m = -1e30f;
#pragma unroll
      for (int c = 0; c < CC; ++c) { v[c] = row[c]; m = fmaxf(m, v[c]); }
      float s = 0.f;
#pragma unroll
      for (int c = 0; c < CC; ++c) { v[c] = __expf(v[c] - m); s += v[c]; }
      float inv = 1.f / s;
      float* o = lps + (tl * 128 + l) * 12;
#pragma unroll
      for (int c = 0; c < CC; ++c) o[c] = v[c] * inv;
      o[10] = 0.f; o[11] = 0.f;
    }
    __syncthreads();

#pragma unroll
    for (int jj = 0; jj < 4; ++jj) {
      int idx = tid + 256 * jj;           // 0..1023 = (tl, s, lane)
      int tl = idx >> 9, rem = idx & 511;
      int s = rem >> 6, lane = rem & 63;
      int hf = lane >> 5, n = lane & 31;
      unsigned int wd[4];
#pragma unroll
      for (int jp = 0; jp < 4; ++jp) {
        int l0 = s * 16 + hf * 8 + jp * 2;
        float f0 = (n < CC) ? lps[(tl * 128 + l0) * 12 + n] : 0.f;
        float f1 = (n < CC) ? lps[(tl * 128 + l0 + 1) * 12 + n] : 0.f;
        wd[jp] = pkbf(f0, f1);
      }
      ((uint4*)lpb)[(size_t)(t0 + tl) * 512 + s * 64 + lane] =
          make_uint4(wd[0], wd[1], wd[2], wd[3]);
    }
  }
}

// ---------------- Kernel 2: main contraction via MFMA -----------------------
// grid (64 bg of 128 b, 16 tg of 8 trees); block 256 = 4 waves.
__global__ __launch_bounds__(256, 4) void main_kernel(
    const float* __restrict__ sT, const float* __restrict__ attnT,
    const unsigned int* __restrict__ lpb, float* __restrict__ partial) {
  __shared__ float red[128 * 10];
  const int bg = blockIdx.x, tg = blockIdx.y;
  const int tid = threadIdx.x;
  const int w = tid >> 6, lane = tid & 63;
  const int half = lane >> 5;
  const int b = bg * 128 + w * 32 + (lane & 31);

  floatx16 acc;
#pragma unroll
  for (int i = 0; i < 16; ++i) acc[i] = 0.f;

#pragma unroll 1
  for (int it = 0; it < 8; ++it) {
    const int t = tg * 8 + it;
    uint4 bf[8];
    const uint4* lpt = (const uint4*)lpb + (size_t)t * 512 + lane;
#pragma unroll
    for (int s = 0; s < 8; ++s) bf[s] = lpt[s * 64];

    const float* sp = sT + (size_t)t * 7 * BB + b;
    float s0 = sp[0 * BB], s1 = sp[1 * BB], s2 = sp[2 * BB], s3 = sp[3 * BB];
    float s4 = sp[4 * BB], s5 = sp[5 * BB], s6 = sp[6 * BB];
    float A = attnT[(size_t)t * BB + b];

    float s0c = 1.f - s0, s1c = 1.f - s1, s2c = 1.f - s2;
    float t0 = s0 * s1, t1 = s0c * s1, t2 = s0 * s1c, t3 = s0c * s1c;
    float pl[8];
    pl[0] = t0 * s2;  pl[1] = t1 * s2;  pl[2] = t2 * s2;  pl[3] = t3 * s2;
    pl[4] = t0 * s2c; pl[5] = t1 * s2c; pl[6] = t2 * s2c; pl[7] = t3 * s2c;
    float sel3 = half ? (1.f - s3) : s3;
    float Af = A * sel3;
    float s4c = 1.f - s4, s5c = 1.f - s5;
    float as6 = Af * s6, as6c = Af * (1.f - s6);
    float u0 = s4 * s5, u1 = s4c * s5, u2 = s4 * s5c, u3 = s4c * s5c;
    float wv[8];
    wv[0] = u0 * as6;  wv[1] = u1 * as6;  wv[2] = u2 * as6;  wv[3] = u3 * as6;
    wv[4] = u0 * as6c; wv[5] = u1 * as6c; wv[6] = u2 * as6c; wv[7] = u3 * as6c;

#pragma unroll
    for (int s = 0; s < 8; ++s) {
      float ws = wv[s];
      union { short8 v; unsigned int u[4]; } a;
#pragma unroll
      for (int jp = 0; jp < 4; ++jp)
        a.u[jp] = pkbf(pl[jp * 2] * ws, pl[jp * 2 + 1] * ws);
      acc = __builtin_amdgcn_mfma_f32_32x32x16_bf16(
          a.v, *(const short8*)&bf[s], acc, 0, 0, 0);
    }
  }

  const int col = lane & 31;
  if (col < CC) {
#pragma unroll
    for (int r = 0; r < 16; ++r) {
      int row = (r & 3) + 8 * (r >> 2) + 4 * half;
      red[(w * 32 + row) * 10 + col] = acc[r];
    }
  }
  __syncthreads();
#pragma unroll
  for (int j = 0; j < 5; ++j) {
    int idx = tid + 256 * j;   // 0..1279
    partial[(size_t)tg * 81920 + (size_t)bg * 1280 + idx] = red[idx];
  }
}

// ---------------- Kernel 3: final reduce over 16 tree-groups ----------------
__global__ __launch_bounds__(256) void reduce_kernel(
    const float* __restrict__ partial, float* __restrict__ out) {
  int idx = blockIdx.x * 256 + threadIdx.x;  // 0..81919
  float s = 0.f;
#pragma unroll
  for (int tg = 0; tg < 16; ++tg) s += partial[(size_t)tg * 81920 + idx];
  out[idx] = s;
}

// ---------------------------------------------------------------------------
extern "C" void kernel_launch(void* const* d_in, const int* in_sizes, int n_in,
                              void* d_out, int out_size, void* d_ws, size_t ws_size,
                              hipStream_t stream) {
  const float* x    = (const float*)d_in[0];
  const float* mask = (const float*)d_in[1];
  const float* thr  = (const float*)d_in[2];
  const float* lo   = (const float*)d_in[3];
  const float* W1   = (const float*)d_in[4];
  const float* b1   = (const float*)d_in[5];
  const float* W2   = (const float*)d_in[6];
  const float* b2   = (const float*)d_in[7];
  float* out = (float*)d_out;
  float* ws  = (float*)d_ws;

  float*        sT      = ws + OFF_S;
  float*        attnT   = ws + OFF_AT;
  unsigned int* LPb     = (unsigned int*)(ws + OFF_LPB);
  float*        partial = ws + OFF_PT;

  phase1_kernel<<<1472, 256, 0, stream>>>(x, mask, thr, lo, W1, b1, W2, b2,
                                          sT, attnT, LPb);
  main_kernel<<<dim3(64, 16), 256, 0, stream>>>(sT, attnT, LPb, partial);
  reduce_kernel<<<320, 256, 0, stream>>>(partial, out);
}